// Round 3
// baseline (108.135 us; speedup 1.0000x reference)
//
#include <hip/hip_runtime.h>
#include <math.h>

#define NB 1024
#define NN 512
#define ND 128

__global__ __launch_bounds__(256) void darp_decoder_kernel(
    const float* __restrict__ node_emb,
    const float* __restrict__ W_last,
    const float* __restrict__ W_first,
    const float* __restrict__ W_graph,
    const float* __restrict__ W_visited,
    const float* __restrict__ W_key,
    const float* __restrict__ W_state,
    const float* __restrict__ b_state,
    const float* __restrict__ current_time,
    const float* __restrict__ used_capacity,
    const float* __restrict__ vehicle_capacity,
    const float* __restrict__ ttm,
    const int* __restrict__ current_node,
    const int* __restrict__ previous_action,
    const int* __restrict__ first_node,
    const int* __restrict__ visited,        // bool materialized as int32
    const int* __restrict__ action_mask,    // bool materialized as int32
    const int* __restrict__ step_i,
    const int* __restrict__ h3_indices,
    float* __restrict__ out)                // reference output dtype: float32
{
    const int b    = blockIdx.x;
    const int t    = threadIdx.x;
    const int wave = t >> 6;
    const int lane = t & 63;
    const int l5   = lane & 31;   // lane within 32-lane half
    const int strm = t >> 5;      // 0..7 row-stream id (wave*2 + half)

    __shared__ float4 sredg[8][32];
    __shared__ float4 sredv[8][32];
    __shared__ float  smean[ND];
    __shared__ float  svis[ND];
    __shared__ float  shcur[ND];
    __shared__ float  shfirst[ND];
    __shared__ float  qs[ND];
    __shared__ float  qp[ND];
    __shared__ float  scores[NN];
    __shared__ float  sred[8];
    __shared__ float  s_scal[4];

    const float* nb = node_emb + (size_t)b * NN * ND;

    // ---------------- Phase A1: column sums over n (graph mean + visited-weighted) ----
    {
        float4 g = make_float4(0.f, 0.f, 0.f, 0.f);
        float4 v = make_float4(0.f, 0.f, 0.f, 0.f);
        const int* visb = visited + (size_t)b * NN;
        const float* colp = nb + (size_t)strm * 64 * ND + l5 * 4;
        for (int k = 0; k < 64; ++k) {
            float4 x = *reinterpret_cast<const float4*>(colp + (size_t)k * ND);
            float vf = visb[strm * 64 + k] ? 1.0f : 0.0f;
            g.x += x.x; g.y += x.y; g.z += x.z; g.w += x.w;
            v.x = fmaf(vf, x.x, v.x); v.y = fmaf(vf, x.y, v.y);
            v.z = fmaf(vf, x.z, v.z); v.w = fmaf(vf, x.w, v.w);
        }
        sredg[strm][l5] = g;
        sredv[strm][l5] = v;
    }
    __syncthreads();

    // ---------------- Phase A2: vcount reduce + column finalize + gathers ------------
    float vc = (visited[(size_t)b * NN + t]       ? 1.f : 0.f)
             + (visited[(size_t)b * NN + t + 256] ? 1.f : 0.f);
#pragma unroll
    for (int off = 32; off >= 1; off >>= 1) vc += __shfl_xor(vc, off);
    if (lane == 0) sred[wave] = vc;

    int cur  = current_node[b];
    int prev = previous_action[b];
    int fn   = first_node[b];
    if (prev == 0 && cur != 0) fn = cur;
    if (cur == 0) fn = 0;

    if (t < 128) {
        shcur[t]   = nb[(size_t)cur * ND + t];
        shfirst[t] = nb[(size_t)fn  * ND + t];
    }

    if (t < 32) {
        float4 g = sredg[0][t];
        float4 v = sredv[0][t];
#pragma unroll
        for (int j = 1; j < 8; ++j) {
            float4 a = sredg[j][t], c = sredv[j][t];
            g.x += a.x; g.y += a.y; g.z += a.z; g.w += a.w;
            v.x += c.x; v.y += c.y; v.z += c.z; v.w += c.w;
        }
        const float invN = 1.0f / (float)NN;
        smean[t * 4 + 0] = g.x * invN; smean[t * 4 + 1] = g.y * invN;
        smean[t * 4 + 2] = g.z * invN; smean[t * 4 + 3] = g.w * invN;
        svis[t * 4 + 0] = v.x; svis[t * 4 + 1] = v.y;
        svis[t * 4 + 2] = v.z; svis[t * 4 + 3] = v.w;
    }
    __syncthreads();

    if (t == 0) {
        float c = sred[0] + sred[1] + sred[2] + sred[3];
        s_scal[0] = 1.0f / fmaxf(c, 1.0f);
        s_scal[1] = vehicle_capacity[b] - used_capacity[b];
        s_scal[2] = current_time[b] * (1.0f / 1440.0f);
        s_scal[3] = (float)step_i[b] * (1.0f / (2.0f * (float)NN));
    }
    __syncthreads();

    if (t < 128) svis[t] *= s_scal[0];   // h_visited = vsum / vcount
    __syncthreads();

    // ---------------- Phase A3: q[e] = sum of 4 small matvecs + state feats ----------
    if (t < 128) {
        float acc = b_state[t]
                  + s_scal[1] * W_state[t]
                  + s_scal[2] * W_state[128 + t]
                  + s_scal[3] * W_state[256 + t];
        for (int d = 0; d < 128; ++d) {
            acc = fmaf(shcur[d],   W_last[d * 128 + t],    acc);
            acc = fmaf(shfirst[d], W_first[d * 128 + t],   acc);
            acc = fmaf(smean[d],   W_graph[d * 128 + t],   acc);
            acc = fmaf(svis[d],    W_visited[d * 128 + t], acc);
        }
        qs[t] = acc;
    }
    __syncthreads();

    // ---------------- Phase A4: q'[d] = (W_key @ q)[d] / sqrt(D) ---------------------
    {
        float4 qv = *reinterpret_cast<const float4*>(&qs[l5 * 4]);
#pragma unroll
        for (int it = 0; it < 16; ++it) {
            int d = it * 8 + strm;
            float4 wk = *reinterpret_cast<const float4*>(W_key + d * 128 + l5 * 4);
            float s = wk.x * qv.x + wk.y * qv.y + wk.z * qv.z + wk.w * qv.w;
            s += __shfl_xor(s, 16); s += __shfl_xor(s, 8);
            s += __shfl_xor(s, 4);  s += __shfl_xor(s, 2); s += __shfl_xor(s, 1);
            if (l5 == 0) qp[d] = s * 0.08838834764831845f;  // 1/sqrt(128)
        }
    }
    __syncthreads();

    // ---------------- Phase B1: score[n] = q' . node_emb[b,n,:] ----------------------
    {
        float4 qv = *reinterpret_cast<const float4*>(&qp[l5 * 4]);
        for (int it = 0; it < 64; ++it) {
            int n = it * 8 + strm;
            float4 x = *reinterpret_cast<const float4*>(nb + (size_t)n * ND + l5 * 4);
            float s = x.x * qv.x + x.y * qv.y + x.z * qv.z + x.w * qv.w;
            s += __shfl_xor(s, 16); s += __shfl_xor(s, 8);
            s += __shfl_xor(s, 4);  s += __shfl_xor(s, 2); s += __shfl_xor(s, 1);
            if (l5 == 0) scores[n] = s;
        }
    }
    __syncthreads();

    // ---------------- Phase B2: travel adjust + tanh clip + mask + log_softmax -------
    {
        const int    cur_h3 = h3_indices[(size_t)b * NN + cur];
        const float* trow   = ttm + (size_t)cur_h3 * NN;
        const float  tscale = 1.0f / (1440.0f * 1.4142135623730951f);

        const int n1 = t, n2 = t + 256;
        float s1 = scores[n1], s2 = scores[n2];
        int h1 = h3_indices[(size_t)b * NN + n1];
        int h2 = h3_indices[(size_t)b * NN + n2];
        s1 -= trow[h1] * tscale;
        s2 -= trow[h2] * tscale;
        s1 = 10.0f * tanhf(s1 * 0.1f);
        s2 = 10.0f * tanhf(s2 * 0.1f);
        if (!action_mask[(size_t)b * NN + n1]) s1 = -1e8f;
        if (!action_mask[(size_t)b * NN + n2]) s2 = -1e8f;

        float m = fmaxf(s1, s2);
#pragma unroll
        for (int off = 32; off >= 1; off >>= 1) m = fmaxf(m, __shfl_xor(m, off));
        if (lane == 0) sred[wave] = m;
        __syncthreads();
        float bm = fmaxf(fmaxf(sred[0], sred[1]), fmaxf(sred[2], sred[3]));

        float es = expf(s1 - bm) + expf(s2 - bm);
#pragma unroll
        for (int off = 32; off >= 1; off >>= 1) es += __shfl_xor(es, off);
        if (lane == 0) sred[4 + wave] = es;
        __syncthreads();
        float lse = bm + logf(sred[4] + sred[5] + sred[6] + sred[7]);

        out[(size_t)b * NN + n1] = s1 - lse;
        out[(size_t)b * NN + n2] = s2 - lse;
    }
}

extern "C" void kernel_launch(void* const* d_in, const int* in_sizes, int n_in,
                              void* d_out, int out_size, void* d_ws, size_t ws_size,
                              hipStream_t stream) {
    (void)in_sizes; (void)n_in; (void)d_ws; (void)ws_size; (void)out_size;
    darp_decoder_kernel<<<dim3(NB), dim3(256), 0, stream>>>(
        (const float*)d_in[0],   // node_emb
        (const float*)d_in[1],   // W_last
        (const float*)d_in[2],   // W_first
        (const float*)d_in[3],   // W_graph
        (const float*)d_in[4],   // W_visited
        (const float*)d_in[5],   // W_key
        (const float*)d_in[6],   // W_state
        (const float*)d_in[7],   // b_state
        (const float*)d_in[8],   // current_time
        (const float*)d_in[9],   // used_capacity
        (const float*)d_in[10],  // vehicle_capacity
        (const float*)d_in[11],  // travel_time_matrix
        (const int*)d_in[12],    // current_node
        (const int*)d_in[13],    // previous_action
        (const int*)d_in[14],    // first_node
        (const int*)d_in[15],    // visited (bool as int32)
        (const int*)d_in[16],    // action_mask (bool as int32)
        (const int*)d_in[17],    // i
        (const int*)d_in[18],    // h3_indices
        (float*)d_out);
}